// Round 18
// baseline (4371.497 us; speedup 1.0000x reference)
//
#include <hip/hip_runtime.h>

typedef float f32x2 __attribute__((ext_vector_type(2)));
typedef float f32x4 __attribute__((ext_vector_type(4)));
typedef _Float16 f16x2 __attribute__((ext_vector_type(2)));
typedef _Float16 f16x4 __attribute__((ext_vector_type(4)));
typedef _Float16 f16x8 __attribute__((ext_vector_type(8)));

#define BB 64
#define TT 1024
#define DIN 128
#define NB 256
#define KW 5
#define HID 512
#define LL 510
#define LT 32
#define ROWS 2048         // 4*HID
#define BPB 4             // blocks per batch
#define PRQ 512           // local rows per block (4 gates x 128 units)
#define RGQ 128           // row-groups (4 rows) per block
#define CS 16             // xp chunk size (timesteps)
#define PAYF 128          // floats per (block,buf) payload slot (512B)
#define NHH4 (PRQ*HID)    // 262144 halves per quarter (2^18)
#define NIH4 (PRQ*NB)     // 131072 halves per quarter (2^17)
#define EPS 1e-5f

__device__ __forceinline__ float sigm(float x) { return 1.f/(1.f + expf(-x)); }

#if __has_builtin(__builtin_amdgcn_fdot2)
#define FDOT2(a, b, c) __builtin_amdgcn_fdot2((a), (b), (c), false)
#else
#define FDOT2(a, b, c) ((float)(a)[0]*(float)(b)[0] + (float)(a)[1]*(float)(b)[1] + (c))
#endif
#define SH(w, i) __builtin_shufflevector((w), (w), 2*(i), 2*(i)+1)

// ---------------- coherent helpers (sc0 sc1: write-through / bypass loads) --------
__device__ __forceinline__ void st2_sys(_Float16* p, _Float16 v) {
  unsigned ui = (unsigned)__builtin_bit_cast(unsigned short, v);
  asm volatile("global_store_short %0, %1, off sc0 sc1" :: "v"(p), "v"(ui) : "memory");
}
__device__ __forceinline__ void st4f_sys(float* p, float v) {
  asm volatile("global_store_dword %0, %1, off sc0 sc1" :: "v"(p), "v"(v) : "memory");
}
__device__ __forceinline__ void st4_sys_u32(unsigned* p, unsigned v) {
  asm volatile("global_store_dword %0, %1, off sc0 sc1" :: "v"(p), "v"(v) : "memory");
}
__device__ __forceinline__ unsigned ld4_sys_u32(const unsigned* p) {
  unsigned v;
  asm volatile("global_load_dword %0, %1, off sc0 sc1\n\ts_waitcnt vmcnt(0)"
               : "=v"(v) : "v"(p) : "memory");
  return v;
}
__device__ __forceinline__ f32x4 ld16_sys1(const float* a) {
  f32x4 r;
  asm volatile("global_load_dwordx4 %0, %1, off sc0 sc1\n\ts_waitcnt vmcnt(0)"
               : "=v"(r) : "v"(a) : "memory");
  return r;
}
__device__ __forceinline__ void ld8x3_sys(const float* a0, const float* a1,
                                          const float* a2,
                                          f32x2& r0, f32x2& r1, f32x2& r2) {
  asm volatile(
      "global_load_dwordx2 %0, %3, off sc0 sc1\n\t"
      "global_load_dwordx2 %1, %4, off sc0 sc1\n\t"
      "global_load_dwordx2 %2, %5, off sc0 sc1\n\t"
      "s_waitcnt vmcnt(0)"
      : "=&v"(r0), "=&v"(r1), "=&v"(r2)
      : "v"(a0), "v"(a1), "v"(a2)
      : "memory");
}

// ---- prep: COLUMN-SPLIT packing (round-17). Quarter p owns units
// [128p,128p+128) for all 4 gates: rl in [0,512) -> r = (rl>>7)*512+128p+(rl&127).
__global__ __launch_bounds__(256) void prep_kernel(
    const float* __restrict__ wih, const float* __restrict__ whh,
    const float* __restrict__ bih, const float* __restrict__ bhh,
    _Float16* __restrict__ whhP4, _Float16* __restrict__ wihP4,
    float* __restrict__ biasvP)
{
  const int e = blockIdx.x*256 + threadIdx.x;
  if (e < 4*NHH4) {
    const int p = e >> 18, e2 = e & (NHH4-1);
    const int kp = e2 >> 10, rg = (e2 >> 3) & 127, s = e2 & 7;
    const int rl = 4*rg + (s >> 1);
    const int r = ((rl >> 7) << 9) + (p << 7) + (rl & 127);
    const int k = 2*kp + (s & 1);
    whhP4[e] = (_Float16)whh[(size_t)r*HID + k];
  } else if (e < 4*NHH4 + 4*NIH4) {
    const int f = e - 4*NHH4;
    const int p = f >> 17, f2 = f & (NIH4-1);
    const int kp = f2 >> 10, rg = (f2 >> 3) & 127, s = f2 & 7;
    const int rl = 4*rg + (s >> 1);
    const int r = ((rl >> 7) << 9) + (p << 7) + (rl & 127);
    const int k = 2*kp + (s & 1);
    wihP4[f] = (_Float16)wih[(size_t)r*NB + k];
  } else if (e < 4*NHH4 + 4*NIH4 + ROWS) {
    const int idx = e - 4*NHH4 - 4*NIH4;
    const int p = idx >> 9, rl = idx & 511;
    const int r = ((rl >> 7) << 9) + (p << 7) + (rl & 127);
    biasvP[idx] = bih[r] + bhh[r];
  }
}

// ---------------- Conv1d + ReLU + BatchNorm (eval) -> seq[B][L][NB] ----------------
__global__ __launch_bounds__(256) void conv_kernel(
    const float* __restrict__ x, const float* __restrict__ cw,
    const float* __restrict__ cb, const float* __restrict__ gma,
    const float* __restrict__ bta, const float* __restrict__ bmean,
    const float* __restrict__ bvar, float* __restrict__ seq)
{
  __shared__ float xt[2*LT+3][DIN];
  const int b = blockIdx.y, lc = blockIdx.x, tid = threadIdx.x;
  const int l0 = lc*LT, t0 = l0*2;

  const float4* x4 = (const float4*)(x + ((size_t)b*TT + t0)*DIN);
  for (int i = tid; i < (2*LT+3)*(DIN/4); i += 256) {
    const int r = i >> 5, c = i & 31;
    float4 v = make_float4(0.f, 0.f, 0.f, 0.f);
    if (t0 + r < TT) v = x4[(size_t)r*(DIN/4) + c];
    ((float4*)xt[r])[c] = v;
  }
  __syncthreads();

  const int f = tid;
  float acc[LT];
#pragma unroll
  for (int l = 0; l < LT; ++l) acc[l] = 0.f;

  const float* wr = cw + (size_t)f*(DIN*KW);
  for (int d = 0; d < DIN; ++d) {
    float xr[2*LT+3];
#pragma unroll
    for (int r = 0; r < 2*LT+3; ++r) xr[r] = xt[r][d];
#pragma unroll
    for (int k = 0; k < KW; ++k) {
      const float w = wr[d*KW + k];
#pragma unroll
      for (int l = 0; l < LT; ++l) acc[l] += w * xr[2*l + k];
    }
  }

  const float bias  = cb[f];
  const float scale = gma[f] * rsqrtf(bvar[f] + EPS);
  const float shift = bta[f] - bmean[f]*scale;
#pragma unroll
  for (int l = 0; l < LT; ++l) {
    const int ll = l0 + l;
    if (ll < LL) {
      float y = acc[l] + bias;
      y = fmaxf(y, 0.f);
      seq[((size_t)b*LL + ll)*NB + f] = y*scale + shift;
    }
  }
}

// one GEMV k-slice for this thread (32 k-pairs); result -> part[] or accS regs
#define WHH_SLICE()                                                     \
  {                                                                     \
    float a0=0.f, a1=0.f, a2=0.f, a3=0.f;                               \
    const f16x8* wp = (const f16x8*)whhB + ((size_t)(32*kh))*RGQ + rg;  \
    const _Float16* zp = zs + 64*kh;                                    \
    _Pragma("unroll 8")                                                 \
    for (int kp = 0; kp < 32; ++kp) {                                   \
      const f16x8 w = wp[(size_t)kp*RGQ];                               \
      const f16x2 z = *(const f16x2*)(zp + 2*kp);                       \
      a0 = FDOT2(SH(w,0), z, a0);                                       \
      a1 = FDOT2(SH(w,1), z, a1);                                       \
      a2 = FDOT2(SH(w,2), z, a2);                                       \
      a3 = FDOT2(SH(w,3), z, a3);                                       \
    }                                                                   \
    if (kh) part[kh-1][rg] = f32x4{a0, a1, a2, a3};                     \
    else    accS = f32x4{a0, a1, a2, a3};                               \
  }

// ---------------- SkipLSTM recurrence: COLUMN-SPLIT + PIPELINED GEMV --------------
// 256 blocks x 1024 threads; block (b = blk>>2, p = blk&3) owns all 4 gates for
// units [128p,128p+128). PIPELINE: since h,c freeze during skip steps, the
// W_hh.h GEMV for the NEXT update step is computed early, split in two:
//   phase A (kh in {2p,2p+1}, own-k, h-slice fresh locally) runs BETWEEN the
//   flag store and the poll -> exchange latency hidden under compute;
//   phase B (other 6 kh groups, partner-k) runs after partner h arrives.
// Pending result lives in part[]/accS across skips; xp[t] + bias + act applied
// at consumption. Per-thread accumulation order identical to round 17 ->
// bit-identical gates. Flag/payload protocol verbatim from round 9/17.
__global__ __launch_bounds__(1024) void rec_kernel(
    const float* __restrict__ seq, const _Float16* __restrict__ whhP4,
    const _Float16* __restrict__ wihP4, const float* __restrict__ biasvP,
    const float* __restrict__ wu, const float* __restrict__ bu,
    float* __restrict__ pay, unsigned* __restrict__ flags,
    float* __restrict__ out)
{
  __shared__ float xp[CS][PRQ];               // 32 KB
  __shared__ f16x2 seqc[CS][NB/2];            //  8 KB
  __shared__ alignas(16) _Float16 zs[HID];    //  1 KB (full h, fp16)
  __shared__ f32x4 part[7][RGQ];              // 14 KB
  __shared__ float gown[PRQ];                 //  2 KB
  __shared__ float pw[2];
  __shared__ int   u_lds;

  const int tid = threadIdx.x;
  const int rg  = tid & 127, kh = tid >> 7;   // kh in [0,8)
  const int blk = blockIdx.x, b = blk >> 2, p = blk & 3;
  const bool inA = (kh >> 1) == p;            // own-k groups {2p, 2p+1}
  const float* seqb = seq + (size_t)b*LL*NB;
  const _Float16* whhB = whhP4 + (size_t)p*NHH4;
  const _Float16* wihB = wihP4 + (size_t)p*NIH4;
  float* pay_own = pay + (size_t)blk*2*PAYF;
  const float* pay_b = pay + (size_t)(b*BPB)*2*PAYF;
  unsigned* flags_b = flags + (size_t)b*BPB*32;

  f32x4 bias4 = {0.f,0.f,0.f,0.f};
  if (kh == 0) bias4 = ((const f32x4*)(biasvP + p*PRQ))[rg];
  const float wuj = (tid < 128) ? wu[128*p + tid] : 0.f;
  const float buv = bu[0];

  f32x4 accS = {0.f,0.f,0.f,0.f};             // kh==0 pending GEMV slice
  float c_reg = 0.f, h_out = 0.f;             // unit (tid) state, tid<128
  float ut_r = 1.f, dot_r = 0.f;              // thread-0 scalar state
  int ustep = 0;

  // prime: pending GEMV = W_hh . h0 = 0
  if (tid < 7*RGQ) ((f32x4*)part)[tid] = f32x4{0.f,0.f,0.f,0.f};
  if (tid < 128)
    *(f16x4*)(zs + 4*tid) = (f16x4){(_Float16)0,(_Float16)0,(_Float16)0,(_Float16)0};
  if (tid == 0) u_lds = 1;
  __syncthreads();

  for (int t0 = 0; t0 < LL; t0 += CS) {
    // ---- stage x chunk as fp16 pairs ----
    {
      const int tt = tid >> 7, kp = tid & 127;
#pragma unroll
      for (int o = 0; o < CS; o += 8) {
        const int ttt = tt + o;
        f16x2 v = {(_Float16)0, (_Float16)0};
        if (t0 + ttt < LL) {
          const float* sp = seqb + (size_t)(t0+ttt)*NB + 2*kp;
          v[0] = (_Float16)sp[0]; v[1] = (_Float16)sp[1];
        }
        seqc[ttt][kp] = v;
      }
    }
    __syncthreads();

    // ---- xp chunk GEMM: thread (rg, kh) -> rows 4rg..4rg+3, timesteps 2kh,2kh+1 --
    {
      f32x4 acc[2] = {{0,0,0,0},{0,0,0,0}};
      const f16x8* wp = (const f16x8*)wihB + rg;
#pragma unroll 4
      for (int kp = 0; kp < 128; ++kp) {
        const f16x8 w = wp[(size_t)kp*RGQ];
#pragma unroll
        for (int tt = 0; tt < 2; ++tt) {
          const f16x2 z = seqc[2*kh + tt][kp];
          acc[tt].x = FDOT2(SH(w,0), z, acc[tt].x);
          acc[tt].y = FDOT2(SH(w,1), z, acc[tt].y);
          acc[tt].z = FDOT2(SH(w,2), z, acc[tt].z);
          acc[tt].w = FDOT2(SH(w,3), z, acc[tt].w);
        }
      }
#pragma unroll
      for (int tt = 0; tt < 2; ++tt)
        *(f32x4*)&xp[2*kh + tt][4*rg] = acc[tt];
    }
    __syncthreads();

    const int tend = (t0 + CS < LL) ? t0 + CS : LL;
    for (int t = t0; t < tend; ++t) {
      const int u = u_lds;

      if (u) {
        ustep++;
        const int buf = ustep & 1;

        // ---- P2: finalize pending gates: accS/part + bias + xp[t] -> act ----
        if (kh == 0) {
          f32x4 v = accS + bias4 + *(const f32x4*)&xp[t - t0][4*rg];
#pragma unroll
          for (int q = 0; q < 7; ++q) v += part[q][rg];
          const int gate = rg >> 5;
          f32x4 s;
          if (gate == 2) {
            s.x = tanhf(v.x); s.y = tanhf(v.y); s.z = tanhf(v.z); s.w = tanhf(v.w);
          } else {
            s.x = sigm(v.x); s.y = sigm(v.y); s.z = sigm(v.z); s.w = sigm(v.w);
          }
          *(f32x4*)&gown[4*rg] = s;
        }
        __syncthreads();                        // (1) gown ready

        // ---- P3: local state update (unit jj = tid), payload store ----
        if (tid < 128) {
          const int jj = tid;
          const float ig = gown[jj],       fg = gown[128 + jj];
          const float gg = gown[256 + jj], og = gown[384 + jj];
          const float ct = fg*c_reg + ig*gg;    // u==1 exact: c = cnew
          const float ht = og * tanhf(ct);
          c_reg = ct; h_out = ht;
          const _Float16 hh = (_Float16)ht;
          zs[128*p + jj] = hh;
          st2_sys((_Float16*)(pay_own + (size_t)buf*PAYF) + jj, hh);
          float pp = ct * wuj;
#pragma unroll
          for (int off = 1; off < 64; off <<= 1) pp += __shfl_xor(pp, off);
          if ((tid & 63) == 0) {
            pw[tid >> 6] = pp;
            st4f_sys(pay_own + (size_t)buf*PAYF + 64 + (tid >> 6), pp);
          }
          asm volatile("s_waitcnt vmcnt(0)" ::: "memory");
        }
        __syncthreads();                        // (2) payload drained, zs own fresh

        // ---- P4a: flag store; PHASE A (own-k GEMV for next update); P4b: poll ----
        if (tid == 0) st4_sys_u32(flags_b + p*32, (unsigned)ustep);
        if (inA) WHH_SLICE();                   // overlaps partners' flag latency
        if (tid < 3) {
          const int q = (p + 1 + tid) & 3;
          const unsigned* fp = flags_b + q*32;
          unsigned f = ld4_sys_u32(fp);
          while (f < (unsigned)ustep) {
            __builtin_amdgcn_s_sleep(1);
            f = ld4_sys_u32(fp);
          }
        }
        __syncthreads();                        // (3) partners ready

        // ---- P5: partner h -> zs; tid0: du dot + u decision ----
        if (tid < 48) {
          const int q = tid >> 4, o = tid & 15;
          const int p2 = (p + 1 + q) & 3;
          const float* pp2 = pay_b + ((size_t)p2*2 + buf)*PAYF;
          const f32x4 r = ld16_sys1(pp2 + o*4);
          *(f32x4*)&zs[128*p2 + o*8] = r;
        }
        if (tid == 0) {
          const int q1 = (p+1)&3, q2 = (p+2)&3, q3 = (p+3)&3;
          f32x2 r1, r2, r3;
          ld8x3_sys(pay_b + ((size_t)q1*2 + buf)*PAYF + 64,
                    pay_b + ((size_t)q2*2 + buf)*PAYF + 64,
                    pay_b + ((size_t)q3*2 + buf)*PAYF + 64, r1, r2, r3);
          float dsum[4];
          dsum[p]  = pw[0] + pw[1];
          dsum[q1] = r1.x + r1.y;
          dsum[q2] = r2.x + r2.y;
          dsum[q3] = r3.x + r3.y;
          const float dot = dsum[0] + dsum[1] + dsum[2] + dsum[3];
          const float du = sigm(dot + buv);
          ut_r = du; dot_r = dot;               // u was 1: ut_next = du exactly
          u_lds = (int)rintf(du);
        }
        __syncthreads();                        // (4) zs full, u decided

        // ---- PHASE B: partner-k GEMV for next update ----
        if (!inA) WHH_SLICE();
      } else {
        // ---- skip step: c,h,pending GEMV unchanged; ut/u advance (exact) ----
        if (tid == 0) {
          const float du = sigm(dot_r + buv);
          ut_r = ut_r + fminf(du, 1.f - ut_r);
          u_lds = (int)rintf(ut_r);
        }
      }
      __syncthreads();                          // (5/end) u_lds, part[] visible
    }
  }

  // each block writes ITS disjoint 128-unit slice
  if (tid < 128)
    out[(size_t)b*HID + 128*p + tid] = h_out;
}

extern "C" void kernel_launch(void* const* d_in, const int* in_sizes, int n_in,
                              void* d_out, int out_size, void* d_ws, size_t ws_size,
                              hipStream_t stream) {
  const float* x    = (const float*)d_in[0];
  const float* cw   = (const float*)d_in[1];
  const float* cb   = (const float*)d_in[2];
  const float* gma  = (const float*)d_in[3];
  const float* bta  = (const float*)d_in[4];
  const float* bmean= (const float*)d_in[5];
  const float* bvar = (const float*)d_in[6];
  const float* wih  = (const float*)d_in[7];
  const float* whh  = (const float*)d_in[8];
  const float* bih  = (const float*)d_in[9];
  const float* bhh  = (const float*)d_in[10];
  const float* wu   = (const float*)d_in[11];
  const float* bu   = (const float*)d_in[12];
  float* out = (float*)d_out;

  float* ws       = (float*)d_ws;
  float* seq      = ws;                                    // 8,355,840 f
  _Float16* whhP4 = (_Float16*)(seq + (size_t)BB*LL*NB);   // 4*262144 h (2 MB)
  _Float16* wihP4 = whhP4 + (size_t)4*NHH4;                // 4*131072 h (1 MB)
  float* biasvP   = (float*)(wihP4 + (size_t)4*NIH4);      // 2048 f
  float* pay      = biasvP + ROWS;                         // 256*2*128 f (256 KB)
  unsigned* flags = (unsigned*)(pay + (size_t)BPB*BB*2*PAYF); // 256*32 u32

  hipMemsetAsync(flags, 0, (size_t)BPB*BB*32*sizeof(unsigned), stream);

  hipLaunchKernelGGL(prep_kernel,
                     dim3((4*NHH4 + 4*NIH4 + ROWS + 255)/256), dim3(256),
                     0, stream, wih, whh, bih, bhh, whhP4, wihP4, biasvP);
  hipLaunchKernelGGL(conv_kernel, dim3(16, 64), dim3(256), 0, stream,
                     x, cw, cb, gma, bta, bmean, bvar, seq);
  hipLaunchKernelGGL(rec_kernel, dim3(BPB*BB), dim3(1024), 0, stream,
                     seq, whhP4, wihP4, biasvP, wu, bu, pay, flags, out);
}

// Round 19
// 3762.589 us; speedup vs baseline: 1.1618x; 1.1618x over previous
//
#include <hip/hip_runtime.h>

typedef float f32x2 __attribute__((ext_vector_type(2)));
typedef float f32x4 __attribute__((ext_vector_type(4)));
typedef _Float16 f16x2 __attribute__((ext_vector_type(2)));
typedef _Float16 f16x4 __attribute__((ext_vector_type(4)));
typedef _Float16 f16x8 __attribute__((ext_vector_type(8)));

#define BB 64
#define TT 1024
#define DIN 128
#define NB 256
#define KW 5
#define HID 512
#define LL 510
#define LT 32
#define ROWS 2048         // 4*HID
#define BPB 4             // blocks per batch
#define PRQ 512           // local rows per block (4 gates x 128 units)
#define RGQ 128           // row-groups (4 rows) per block
#define CS 16             // xp chunk size (timesteps)
#define PAYF 160          // floats per (block,buf) payload slot (640B)
#define NCHK 66           // 8B chunks per block: 64 h-chunks + 2 pw-chunks
#define NPOLL (3*NCHK)    // 198 partner chunks polled per block
#define NHH4 (PRQ*HID)    // 262144 halves per quarter
#define NIH4 (PRQ*NB)     // 131072 halves per quarter
#define EPS 1e-5f

__device__ __forceinline__ float sigm(float x) { return 1.f/(1.f + expf(-x)); }

#if __has_builtin(__builtin_amdgcn_fdot2)
#define FDOT2(a, b, c) __builtin_amdgcn_fdot2((a), (b), (c), false)
#else
#define FDOT2(a, b, c) ((float)(a)[0]*(float)(b)[0] + (float)(a)[1]*(float)(b)[1] + (c))
#endif
#define SH(w, i) __builtin_shufflevector((w), (w), 2*(i), 2*(i)+1)

// ---------------- coherent helpers (sc0 sc1: write-through / bypass loads) --------
// 8B chunks are naturally-aligned dwordx2 = single-copy atomic at the coherence
// point -> {data, stamp} in one store is self-validating (no flag, no drain).
__device__ __forceinline__ void st8_sys(float* p, f32x2 v) {
  asm volatile("global_store_dwordx2 %0, %1, off sc0 sc1" :: "v"(p), "v"(v) : "memory");
}
__device__ __forceinline__ f32x2 ld8_sys(const float* p) {
  f32x2 r;
  asm volatile("global_load_dwordx2 %0, %1, off sc0 sc1\n\ts_waitcnt vmcnt(0)"
               : "=v"(r) : "v"(p) : "memory");
  return r;
}

// ---- prep: COLUMN-SPLIT packing (round-17, passing). Quarter p owns units
// [128p,128p+128) for all 4 gates: rl in [0,512) -> r = (rl>>7)*512+128p+(rl&127).
__global__ __launch_bounds__(256) void prep_kernel(
    const float* __restrict__ wih, const float* __restrict__ whh,
    const float* __restrict__ bih, const float* __restrict__ bhh,
    _Float16* __restrict__ whhP4, _Float16* __restrict__ wihP4,
    float* __restrict__ biasvP)
{
  const int e = blockIdx.x*256 + threadIdx.x;
  if (e < 4*NHH4) {
    const int p = e >> 18, e2 = e & (NHH4-1);
    const int kp = e2 >> 10, rg = (e2 >> 3) & 127, s = e2 & 7;
    const int rl = 4*rg + (s >> 1);
    const int r = ((rl >> 7) << 9) + (p << 7) + (rl & 127);
    const int k = 2*kp + (s & 1);
    whhP4[e] = (_Float16)whh[(size_t)r*HID + k];
  } else if (e < 4*NHH4 + 4*NIH4) {
    const int f = e - 4*NHH4;
    const int p = f >> 17, f2 = f & (NIH4-1);
    const int kp = f2 >> 10, rg = (f2 >> 3) & 127, s = f2 & 7;
    const int rl = 4*rg + (s >> 1);
    const int r = ((rl >> 7) << 9) + (p << 7) + (rl & 127);
    const int k = 2*kp + (s & 1);
    wihP4[f] = (_Float16)wih[(size_t)r*NB + k];
  } else if (e < 4*NHH4 + 4*NIH4 + ROWS) {
    const int idx = e - 4*NHH4 - 4*NIH4;
    const int p = idx >> 9, rl = idx & 511;
    const int r = ((rl >> 7) << 9) + (p << 7) + (rl & 127);
    biasvP[idx] = bih[r] + bhh[r];
  }
}

// ---------------- Conv1d + ReLU + BatchNorm (eval) -> seq[B][L][NB] ----------------
__global__ __launch_bounds__(256) void conv_kernel(
    const float* __restrict__ x, const float* __restrict__ cw,
    const float* __restrict__ cb, const float* __restrict__ gma,
    const float* __restrict__ bta, const float* __restrict__ bmean,
    const float* __restrict__ bvar, float* __restrict__ seq)
{
  __shared__ float xt[2*LT+3][DIN];
  const int b = blockIdx.y, lc = blockIdx.x, tid = threadIdx.x;
  const int l0 = lc*LT, t0 = l0*2;

  const float4* x4 = (const float4*)(x + ((size_t)b*TT + t0)*DIN);
  for (int i = tid; i < (2*LT+3)*(DIN/4); i += 256) {
    const int r = i >> 5, c = i & 31;
    float4 v = make_float4(0.f, 0.f, 0.f, 0.f);
    if (t0 + r < TT) v = x4[(size_t)r*(DIN/4) + c];
    ((float4*)xt[r])[c] = v;
  }
  __syncthreads();

  const int f = tid;
  float acc[LT];
#pragma unroll
  for (int l = 0; l < LT; ++l) acc[l] = 0.f;

  const float* wr = cw + (size_t)f*(DIN*KW);
  for (int d = 0; d < DIN; ++d) {
    float xr[2*LT+3];
#pragma unroll
    for (int r = 0; r < 2*LT+3; ++r) xr[r] = xt[r][d];
#pragma unroll
    for (int k = 0; k < KW; ++k) {
      const float w = wr[d*KW + k];
#pragma unroll
      for (int l = 0; l < LT; ++l) acc[l] += w * xr[2*l + k];
    }
  }

  const float bias  = cb[f];
  const float scale = gma[f] * rsqrtf(bvar[f] + EPS);
  const float shift = bta[f] - bmean[f]*scale;
#pragma unroll
  for (int l = 0; l < LT; ++l) {
    const int ll = l0 + l;
    if (ll < LL) {
      float y = acc[l] + bias;
      y = fmaxf(y, 0.f);
      seq[((size_t)b*LL + ll)*NB + f] = y*scale + shift;
    }
  }
}

// one GEMV k-slice for this thread (32 k-pairs); result -> part[] or accS regs
#define WHH_SLICE()                                                     \
  {                                                                     \
    float a0=0.f, a1=0.f, a2=0.f, a3=0.f;                               \
    const f16x8* wp = (const f16x8*)whhB + ((size_t)(32*kh))*RGQ + rg;  \
    const _Float16* zp = zs + 64*kh;                                    \
    _Pragma("unroll 8")                                                 \
    for (int kp = 0; kp < 32; ++kp) {                                   \
      const f16x8 w = wp[(size_t)kp*RGQ];                               \
      const f16x2 z = *(const f16x2*)(zp + 2*kp);                       \
      a0 = FDOT2(SH(w,0), z, a0);                                       \
      a1 = FDOT2(SH(w,1), z, a1);                                       \
      a2 = FDOT2(SH(w,2), z, a2);                                       \
      a3 = FDOT2(SH(w,3), z, a3);                                       \
    }                                                                   \
    if (kh) part[kh-1][rg] = f32x4{a0, a1, a2, a3};                     \
    else    accS = f32x4{a0, a1, a2, a3};                               \
  }

// ---------------- SkipLSTM: COLUMN-SPLIT + SELF-VALIDATING STAMPED EXCHANGE -------
// 256 blocks x 1024 threads; block (b = blk>>2, p = blk&3) owns all 4 gates for
// units [128p,128p+128). Exchange: 8B chunks {2 fp16 h | u32 stamp=ustep}
// (single-copy atomic) -> no flag, no vmcnt drain, 1 poll instead of 3 RTTs.
// Dedicated pollers (tid 128..325) poll 198 partner chunks concurrently with the
// updaters' (tid<128) local update + stores. 3 barriers per update step.
// Overwrite safety: block reaches ustep+2's stores only after reading partners'
// ustep+1 chunks, which partners wrote only after reading OUR ustep chunks
// (same induction as the proven round-9 flag protocol). pay memset per launch
// kills graph-replay stale stamps. Gate/du arithmetic order identical to r17/r18.
__global__ __launch_bounds__(1024) void rec_kernel(
    const float* __restrict__ seq, const _Float16* __restrict__ whhP4,
    const _Float16* __restrict__ wihP4, const float* __restrict__ biasvP,
    const float* __restrict__ wu, const float* __restrict__ bu,
    float* __restrict__ pay, float* __restrict__ out)
{
  __shared__ float xp[CS][PRQ];               // 32 KB
  __shared__ f16x2 seqc[CS][NB/2];            //  8 KB
  __shared__ alignas(16) _Float16 zs[HID];    //  1 KB (full h, fp16)
  __shared__ f32x4 part[7][RGQ];              // 14 KB
  __shared__ float gown[PRQ];                 //  2 KB
  __shared__ float pw_l[2];
  __shared__ float dp[4][2];
  __shared__ int   u_lds;

  const int tid = threadIdx.x;
  const int rg  = tid & 127, kh = tid >> 7;   // kh in [0,8)
  const int blk = blockIdx.x, b = blk >> 2, p = blk & 3;
  const float* seqb = seq + (size_t)b*LL*NB;
  const _Float16* whhB = whhP4 + (size_t)p*NHH4;
  const _Float16* wihB = wihP4 + (size_t)p*NIH4;
  float* pay_own = pay + (size_t)blk*2*PAYF;
  const float* pay_b = pay + (size_t)(b*BPB)*2*PAYF;

  // poller assignment (tid 128..325): one partner chunk each
  const int pg = tid - 128;
  const bool isPoll = (pg >= 0) && (pg < NPOLL);
  const int pq = isPoll ? pg / NCHK : 0;       // partner ordinal 0..2
  const int pc = isPoll ? pg % NCHK : 0;       // chunk id 0..65
  const int pp2 = (p + 1 + pq) & 3;

  f32x4 bias4 = {0.f,0.f,0.f,0.f};
  if (kh == 0) bias4 = ((const f32x4*)(biasvP + p*PRQ))[rg];
  const float wuj = (tid < 128) ? wu[128*p + tid] : 0.f;
  const float buv = bu[0];

  f32x4 accS = {0.f,0.f,0.f,0.f};             // kh==0 pending GEMV slice
  float c_reg = 0.f, h_out = 0.f;             // unit (tid) state, tid<128
  float ut_r = 1.f, dot_r = 0.f;              // thread-0 scalar state
  int ustep = 0;

  // prime: pending GEMV = W_hh . h0 = 0
  if (tid < 7*RGQ) ((f32x4*)part)[tid] = f32x4{0.f,0.f,0.f,0.f};
  if (tid < 128)
    *(f16x4*)(zs + 4*tid) = (f16x4){(_Float16)0,(_Float16)0,(_Float16)0,(_Float16)0};
  if (tid == 0) u_lds = 1;
  __syncthreads();

  for (int t0 = 0; t0 < LL; t0 += CS) {
    // ---- stage x chunk as fp16 pairs ----
    {
      const int tt = tid >> 7, kp = tid & 127;
#pragma unroll
      for (int o = 0; o < CS; o += 8) {
        const int ttt = tt + o;
        f16x2 v = {(_Float16)0, (_Float16)0};
        if (t0 + ttt < LL) {
          const float* sp = seqb + (size_t)(t0+ttt)*NB + 2*kp;
          v[0] = (_Float16)sp[0]; v[1] = (_Float16)sp[1];
        }
        seqc[ttt][kp] = v;
      }
    }
    __syncthreads();

    // ---- xp chunk GEMM: thread (rg, kh) -> rows 4rg..4rg+3, timesteps 2kh,2kh+1 --
    {
      f32x4 acc[2] = {{0,0,0,0},{0,0,0,0}};
      const f16x8* wp = (const f16x8*)wihB + rg;
#pragma unroll 4
      for (int kp = 0; kp < 128; ++kp) {
        const f16x8 w = wp[(size_t)kp*RGQ];
#pragma unroll
        for (int tt = 0; tt < 2; ++tt) {
          const f16x2 z = seqc[2*kh + tt][kp];
          acc[tt].x = FDOT2(SH(w,0), z, acc[tt].x);
          acc[tt].y = FDOT2(SH(w,1), z, acc[tt].y);
          acc[tt].z = FDOT2(SH(w,2), z, acc[tt].z);
          acc[tt].w = FDOT2(SH(w,3), z, acc[tt].w);
        }
      }
#pragma unroll
      for (int tt = 0; tt < 2; ++tt)
        *(f32x4*)&xp[2*kh + tt][4*rg] = acc[tt];
    }
    __syncthreads();

    const int tend = (t0 + CS < LL) ? t0 + CS : LL;
    for (int t = t0; t < tend; ++t) {
      const int u = u_lds;

      if (u) {
        ustep++;
        const int buf = ustep & 1;

        // ---- P1: finalize pending gates: accS/part + bias + xp[t] -> act ----
        if (kh == 0) {
          f32x4 v = accS + bias4 + *(const f32x4*)&xp[t - t0][4*rg];
#pragma unroll
          for (int q = 0; q < 7; ++q) v += part[q][rg];
          const int gate = rg >> 5;
          f32x4 s;
          if (gate == 2) {
            s.x = tanhf(v.x); s.y = tanhf(v.y); s.z = tanhf(v.z); s.w = tanhf(v.w);
          } else {
            s.x = sigm(v.x); s.y = sigm(v.y); s.z = sigm(v.z); s.w = sigm(v.w);
          }
          *(f32x4*)&gown[4*rg] = s;
        }
        __syncthreads();                        // (1) gown ready

        // ---- P2: updaters store stamped chunks  ||  pollers read partners ----
        if (tid < 128) {
          const int jj = tid;
          const float ig = gown[jj],       fg = gown[128 + jj];
          const float gg = gown[256 + jj], og = gown[384 + jj];
          const float ct = fg*c_reg + ig*gg;    // u==1 exact: c = cnew
          const float ht = og * tanhf(ct);
          c_reg = ct; h_out = ht;
          zs[128*p + jj] = (_Float16)ht;
          // stamped h-chunk: {fp16 h(tid), fp16 h(tid+1), u32 ustep}
          const float h1 = __shfl_down(ht, 1);
          if ((tid & 1) == 0) {
            f16x2 hh2; hh2[0] = (_Float16)ht; hh2[1] = (_Float16)h1;
            f32x2 pkt;
            pkt.x = __builtin_bit_cast(float, hh2);
            pkt.y = __uint_as_float((unsigned)ustep);
            st8_sys(pay_own + (size_t)buf*PAYF + tid, pkt);  // chunk c=tid>>1
          }
          // du partial (64-lane reduce), stamped pw-chunks c=64,65
          float pp = ct * wuj;
#pragma unroll
          for (int off = 1; off < 64; off <<= 1) pp += __shfl_xor(pp, off);
          if ((tid & 63) == 0) {
            pw_l[tid >> 6] = pp;
            f32x2 pkt;
            pkt.x = pp;
            pkt.y = __uint_as_float((unsigned)ustep);
            st8_sys(pay_own + (size_t)buf*PAYF + 128 + ((tid >> 6) << 1), pkt);
          }
        } else if (isPoll) {
          const float* a = pay_b + ((size_t)pp2*2 + buf)*PAYF + 2*pc;
          f32x2 r = ld8_sys(a);
          while (__float_as_uint(r.y) != (unsigned)ustep) {
            __builtin_amdgcn_s_sleep(1);
            r = ld8_sys(a);
          }
          if (pc < 64) *(f16x2*)&zs[128*pp2 + 2*pc] = __builtin_bit_cast(f16x2, r.x);
          else         dp[pp2][pc - 64] = r.x;
        }
        __syncthreads();                        // (2) zs full, dp/pw_l ready

        // ---- P3: u decision (tid0) overlapped with GEMV for next step (all) ----
        if (tid == 0) {
          const int q1 = (p+1)&3, q2 = (p+2)&3, q3 = (p+3)&3;
          float dsum[4];
          dsum[p]  = pw_l[0] + pw_l[1];
          dsum[q1] = dp[q1][0] + dp[q1][1];
          dsum[q2] = dp[q2][0] + dp[q2][1];
          dsum[q3] = dp[q3][0] + dp[q3][1];
          const float dot = dsum[0] + dsum[1] + dsum[2] + dsum[3];
          const float du = sigm(dot + buv);
          ut_r = du; dot_r = dot;               // u was 1: ut_next = du exactly
          u_lds = (int)rintf(du);
        }
        WHH_SLICE();                            // pending GEMV for step t+1
      } else {
        // ---- skip step: c,h,pending GEMV unchanged; ut/u advance (exact) ----
        if (tid == 0) {
          const float du = sigm(dot_r + buv);
          ut_r = ut_r + fminf(du, 1.f - ut_r);
          u_lds = (int)rintf(ut_r);
        }
      }
      __syncthreads();                          // (3/end) u_lds, part[] visible
    }
  }

  // each block writes ITS disjoint 128-unit slice
  if (tid < 128)
    out[(size_t)b*HID + 128*p + tid] = h_out;
}

extern "C" void kernel_launch(void* const* d_in, const int* in_sizes, int n_in,
                              void* d_out, int out_size, void* d_ws, size_t ws_size,
                              hipStream_t stream) {
  const float* x    = (const float*)d_in[0];
  const float* cw   = (const float*)d_in[1];
  const float* cb   = (const float*)d_in[2];
  const float* gma  = (const float*)d_in[3];
  const float* bta  = (const float*)d_in[4];
  const float* bmean= (const float*)d_in[5];
  const float* bvar = (const float*)d_in[6];
  const float* wih  = (const float*)d_in[7];
  const float* whh  = (const float*)d_in[8];
  const float* bih  = (const float*)d_in[9];
  const float* bhh  = (const float*)d_in[10];
  const float* wu   = (const float*)d_in[11];
  const float* bu   = (const float*)d_in[12];
  float* out = (float*)d_out;

  float* ws       = (float*)d_ws;
  float* seq      = ws;                                    // 8,355,840 f
  _Float16* whhP4 = (_Float16*)(seq + (size_t)BB*LL*NB);   // 4*262144 h (2 MB)
  _Float16* wihP4 = whhP4 + (size_t)4*NHH4;                // 4*131072 h (1 MB)
  float* biasvP   = (float*)(wihP4 + (size_t)4*NIH4);      // 2048 f
  float* pay      = biasvP + ROWS;                         // 256*2*160 f (320 KB)

  // kill graph-replay stale stamps (deterministic, graph-safe)
  hipMemsetAsync(pay, 0, (size_t)BPB*BB*2*PAYF*sizeof(float), stream);

  hipLaunchKernelGGL(prep_kernel,
                     dim3((4*NHH4 + 4*NIH4 + ROWS + 255)/256), dim3(256),
                     0, stream, wih, whh, bih, bhh, whhP4, wihP4, biasvP);
  hipLaunchKernelGGL(conv_kernel, dim3(16, 64), dim3(256), 0, stream,
                     x, cw, cb, gma, bta, bmean, bvar, seq);
  hipLaunchKernelGGL(rec_kernel, dim3(BPB*BB), dim3(1024), 0, stream,
                     seq, whhP4, wihP4, biasvP, wu, bu, pay, out);
}

// Round 20
// 2853.321 us; speedup vs baseline: 1.5321x; 1.3187x over previous
//
#include <hip/hip_runtime.h>

typedef float f32x2 __attribute__((ext_vector_type(2)));
typedef float f32x4 __attribute__((ext_vector_type(4)));
typedef _Float16 f16x2 __attribute__((ext_vector_type(2)));
typedef _Float16 f16x4 __attribute__((ext_vector_type(4)));
typedef _Float16 f16x8 __attribute__((ext_vector_type(8)));

#define BB 64
#define TT 1024
#define DIN 128
#define NB 256
#define KW 5
#define HID 512
#define LL 510
#define LT 32
#define ROWS 2048         // 4*HID
#define SLC 8             // slices (blocks) per batch-pair group
#define PRS 256           // local rows per slice (4 gates x 64 units)
#define RGS 128           // row-pair groups per slice
#define CS 16             // xp chunk size (timesteps)
#define PAYF 160          // floats per (block,buf) payload slot (640B)
#define NCHK 66           // 8B chunks per block: 64 h (2 batches) + 2 pw
#define NPOLL (7*NCHK)    // 462 partner chunks polled per block
#define NHH8 (1<<17)      // whh halves per slice (256 rows x 512 k)
#define NIH8 (1<<16)      // wih halves per slice (256 rows x 256 k)
#define EPS 1e-5f

__device__ __forceinline__ float sigm(float x) { return 1.f/(1.f + expf(-x)); }

#if __has_builtin(__builtin_amdgcn_fdot2)
#define FDOT2(a, b, c) __builtin_amdgcn_fdot2((a), (b), (c), false)
#else
#define FDOT2(a, b, c) ((float)(a)[0]*(float)(b)[0] + (float)(a)[1]*(float)(b)[1] + (c))
#endif
#define SH(w, i) __builtin_shufflevector((w), (w), 2*(i), 2*(i)+1)

// ---------------- coherent helpers (sc0 sc1: write-through / bypass loads) --------
// 8B naturally-aligned dwordx2 = single-copy atomic -> {data, stamp} stores are
// self-validating (no flag, no drain) — protocol proven in round 19.
__device__ __forceinline__ void st8_sys(float* p, f32x2 v) {
  asm volatile("global_store_dwordx2 %0, %1, off sc0 sc1" :: "v"(p), "v"(v) : "memory");
}
__device__ __forceinline__ f32x2 ld8_sys(const float* p) {
  f32x2 r;
  asm volatile("global_load_dwordx2 %0, %1, off sc0 sc1\n\ts_waitcnt vmcnt(0)"
               : "=v"(r) : "v"(p) : "memory");
  return r;
}

// ---- prep: 8-way COLUMN-SPLIT packing. Slice s owns units [64s,64s+64) x 4 gates.
// local row rl in [0,256) -> global r = (rl>>6)*512 + 64s + (rl&63).
// f16x8 tile = {2 rows x 4 k}: h in [0,8): r01=(h>>1)&1, koff=(h&1)+2*(h>>2);
// e = slice_base + (kqq*RGS + rg)*8 + h ; rl = 2rg+r01 ; k = 4*kqq+koff.
__global__ __launch_bounds__(256) void prep_kernel(
    const float* __restrict__ wih, const float* __restrict__ whh,
    const float* __restrict__ bih, const float* __restrict__ bhh,
    _Float16* __restrict__ whhP8, _Float16* __restrict__ wihP8,
    float* __restrict__ biasvP8)
{
  const int e = blockIdx.x*256 + threadIdx.x;
  if (e < 8*NHH8) {
    const int s = e >> 17, e2 = e & (NHH8-1);
    const int kqq = e2 >> 10, rg = (e2 >> 3) & 127, h = e2 & 7;
    const int r01 = (h >> 1) & 1, koff = (h & 1) + 2*(h >> 2);
    const int rl = 2*rg + r01;
    const int r = ((rl >> 6) << 9) + (s << 6) + (rl & 63);
    const int k = 4*kqq + koff;
    whhP8[e] = (_Float16)whh[(size_t)r*HID + k];
  } else if (e < 8*NHH8 + 8*NIH8) {
    const int f = e - 8*NHH8;
    const int s = f >> 16, f2 = f & (NIH8-1);
    const int kqq = f2 >> 10, rg = (f2 >> 3) & 127, h = f2 & 7;
    const int r01 = (h >> 1) & 1, koff = (h & 1) + 2*(h >> 2);
    const int rl = 2*rg + r01;
    const int r = ((rl >> 6) << 9) + (s << 6) + (rl & 63);
    const int k = 4*kqq + koff;
    wihP8[f] = (_Float16)wih[(size_t)r*NB + k];
  } else if (e < 8*NHH8 + 8*NIH8 + ROWS) {
    const int idx = e - 8*NHH8 - 8*NIH8;
    const int s = idx >> 8, rl = idx & 255;
    const int r = ((rl >> 6) << 9) + (s << 6) + (rl & 63);
    biasvP8[idx] = bih[r] + bhh[r];
  }
}

// ---------------- Conv1d + ReLU + BatchNorm (eval) -> seq[B][L][NB] ----------------
__global__ __launch_bounds__(256) void conv_kernel(
    const float* __restrict__ x, const float* __restrict__ cw,
    const float* __restrict__ cb, const float* __restrict__ gma,
    const float* __restrict__ bta, const float* __restrict__ bmean,
    const float* __restrict__ bvar, float* __restrict__ seq)
{
  __shared__ float xt[2*LT+3][DIN];
  const int b = blockIdx.y, lc = blockIdx.x, tid = threadIdx.x;
  const int l0 = lc*LT, t0 = l0*2;

  const float4* x4 = (const float4*)(x + ((size_t)b*TT + t0)*DIN);
  for (int i = tid; i < (2*LT+3)*(DIN/4); i += 256) {
    const int r = i >> 5, c = i & 31;
    float4 v = make_float4(0.f, 0.f, 0.f, 0.f);
    if (t0 + r < TT) v = x4[(size_t)r*(DIN/4) + c];
    ((float4*)xt[r])[c] = v;
  }
  __syncthreads();

  const int f = tid;
  float acc[LT];
#pragma unroll
  for (int l = 0; l < LT; ++l) acc[l] = 0.f;

  const float* wr = cw + (size_t)f*(DIN*KW);
  for (int d = 0; d < DIN; ++d) {
    float xr[2*LT+3];
#pragma unroll
    for (int r = 0; r < 2*LT+3; ++r) xr[r] = xt[r][d];
#pragma unroll
    for (int k = 0; k < KW; ++k) {
      const float w = wr[d*KW + k];
#pragma unroll
      for (int l = 0; l < LT; ++l) acc[l] += w * xr[2*l + k];
    }
  }

  const float bias  = cb[f];
  const float scale = gma[f] * rsqrtf(bvar[f] + EPS);
  const float shift = bta[f] - bmean[f]*scale;
#pragma unroll
  for (int l = 0; l < LT; ++l) {
    const int ll = l0 + l;
    if (ll < LL) {
      float y = acc[l] + bias;
      y = fmaxf(y, 0.f);
      seq[((size_t)b*LL + ll)*NB + f] = y*scale + shift;
    }
  }
}

// GEMV k-slice for this thread: rows 2rg,2rg+1 x k in [64kh,64kh+64) x 2 batches.
// k ascends in pairs (same order as prior rounds) -> bit-identical row dots.
#define WHH_SLICE()                                                       \
  {                                                                       \
    float aA0=0.f, aA1=0.f, aB0=0.f, aB1=0.f;                             \
    const f16x8* wp = (const f16x8*)whhB + (size_t)(16*kh)*RGS + rg;      \
    const _Float16* zA = zs0 + 64*kh;                                     \
    const _Float16* zB = zs1 + 64*kh;                                     \
    _Pragma("unroll 8")                                                   \
    for (int kq = 0; kq < 16; ++kq) {                                     \
      const f16x8 w = wp[(size_t)kq*RGS];                                 \
      const f16x2 zA01 = *(const f16x2*)(zA + 4*kq);                      \
      const f16x2 zA23 = *(const f16x2*)(zA + 4*kq + 2);                  \
      const f16x2 zB01 = *(const f16x2*)(zB + 4*kq);                      \
      const f16x2 zB23 = *(const f16x2*)(zB + 4*kq + 2);                  \
      aA0 = FDOT2(SH(w,0), zA01, aA0);                                    \
      aA1 = FDOT2(SH(w,1), zA01, aA1);                                    \
      aA0 = FDOT2(SH(w,2), zA23, aA0);                                    \
      aA1 = FDOT2(SH(w,3), zA23, aA1);                                    \
      aB0 = FDOT2(SH(w,0), zB01, aB0);                                    \
      aB1 = FDOT2(SH(w,1), zB01, aB1);                                    \
      aB0 = FDOT2(SH(w,2), zB23, aB0);                                    \
      aB1 = FDOT2(SH(w,3), zB23, aB1);                                    \
    }                                                                     \
    if (kh) part[kh-1][rg] = f32x4{aA0, aA1, aB0, aB1};                   \
    else    accS = f32x4{aA0, aA1, aB0, aB1};                             \
  }

// ---------------- SkipLSTM: 8-way column-split over BATCH-PAIRS -------------------
// 256 blocks x 1024 threads; block (g = blk>>3, s = blk&7) owns units
// [64s,64s+64) x 4 gates for batches {2g, 2g+1}: per step streams 0.25 MB of
// W_hh CONSUMED BY BOTH BATCHES (2x reuse -> half the per-CU fill of round 19).
// Exchange: round-19 stamped 8B chunks {2 fp16 | stamp} (single-copy atomic, no
// flags/drain); 64 h-chunks (32/batch) + 2 pw-chunks per block; 462 partner
// chunks polled by tid 128..589 concurrently with updaters. Mixed skip handled
// with exact u-blend (u in {0,1}); full-skip (both 0) runs no exchange. Pending
// GEMV pipeline (P1 finalize / P3 compute-next) as round 19. du dot assembled
// in fixed slice order 0..7 -> bitwise-identical u in all 8 blocks.
__global__ __launch_bounds__(1024) void rec_kernel(
    const float* __restrict__ seq, const _Float16* __restrict__ whhP8,
    const _Float16* __restrict__ wihP8, const float* __restrict__ biasvP8,
    const float* __restrict__ wu, const float* __restrict__ bu,
    float* __restrict__ pay, float* __restrict__ out)
{
  __shared__ float xp[CS][2][PRS];            // 32 KB
  __shared__ f16x2 seqc[CS][2][NB/2];         // 16 KB
  __shared__ alignas(16) _Float16 zsb[2][HID];//  2 KB (full h, both batches)
  __shared__ f32x4 part[7][RGS];              // 14 KB
  __shared__ float gown[2][PRS];              //  2 KB
  __shared__ float pw_l[2];
  __shared__ float dp[SLC][2];
  __shared__ int   u_lds[2];

  const int tid = threadIdx.x;
  const int rg  = tid & 127, kh = tid >> 7;   // kh in [0,8)
  const int blk = blockIdx.x, g = blk >> 3, s = blk & 7;
  const int bA = 2*g;
  const _Float16* zs0 = zsb[0];
  const _Float16* zs1 = zsb[1];
  const _Float16* whhB = whhP8 + (size_t)s*NHH8;
  const _Float16* wihB = wihP8 + (size_t)s*NIH8;
  float* pay_own = pay + (size_t)blk*2*PAYF;
  const float* pay_g = pay + (size_t)(g*SLC)*2*PAYF;

  // poller assignment (tid 128..589): one partner chunk each
  const int pg = tid - 128;
  const bool isPoll = (pg >= 0) && (pg < NPOLL);
  const int pq = isPoll ? pg / NCHK : 0;       // partner ordinal 0..6
  const int pc = isPoll ? pg % NCHK : 0;       // chunk id 0..65
  const int ps2 = (s + 1 + pq) & 7;

  f32x2 bias2 = {0.f, 0.f};
  if (kh == 0) bias2 = ((const f32x2*)(biasvP8 + s*PRS))[rg];
  const float wuj = (tid < 128) ? wu[64*s + (tid & 63)] : 0.f;
  const float buv = bu[0];

  f32x4 accS = {0.f,0.f,0.f,0.f};             // kh==0 pending GEMV slice
  float c_reg = 0.f, h_out = 0.f;             // unit state: b01=tid>>6, j=tid&63
  float utr[2] = {1.f, 1.f}, dotr[2] = {0.f, 0.f};  // thread-0 scalar state
  int ustep = 0;

  // prime: pending GEMV = W_hh . h0 = 0
  if (tid < 7*RGS) ((f32x4*)part)[tid] = f32x4{0.f,0.f,0.f,0.f};
  if (tid < 256)
    *(f16x4*)(&zsb[tid >> 7][4*(tid & 127)]) =
        (f16x4){(_Float16)0,(_Float16)0,(_Float16)0,(_Float16)0};
  if (tid == 0) { u_lds[0] = 1; u_lds[1] = 1; }
  __syncthreads();

  for (int t0 = 0; t0 < LL; t0 += CS) {
    // ---- stage x chunk (both batches) as fp16 pairs: 4 slots/thread ----
#pragma unroll
    for (int o = 0; o < 4; ++o) {
      const int idx = o*1024 + tid;
      const int kp2 = idx & 127, b01 = (idx >> 7) & 1, ts = idx >> 8;
      f16x2 v = {(_Float16)0, (_Float16)0};
      if (t0 + ts < LL) {
        const float* sp = seq + ((size_t)(bA + b01)*LL + (t0 + ts))*NB + 2*kp2;
        v[0] = (_Float16)sp[0]; v[1] = (_Float16)sp[1];
      }
      seqc[ts][b01][kp2] = v;
    }
    __syncthreads();

    // ---- xp chunk GEMM: thread (rg,kh): rows 2rg,2rg+1; ts 2kh,2kh+1; 2 batches --
    {
      f32x4 acc[2] = {{0,0,0,0},{0,0,0,0}};   // {A0,A1,B0,B1} per ts
      const f16x8* wp = (const f16x8*)wihB + rg;
#pragma unroll 4
      for (int kq = 0; kq < 64; ++kq) {
        const f16x8 w = wp[(size_t)kq*RGS];
#pragma unroll
        for (int tt = 0; tt < 2; ++tt) {
          const int ts = 2*kh + tt;
          const f16x2 zA01 = seqc[ts][0][2*kq],   zA23 = seqc[ts][0][2*kq+1];
          const f16x2 zB01 = seqc[ts][1][2*kq],   zB23 = seqc[ts][1][2*kq+1];
          acc[tt].x = FDOT2(SH(w,0), zA01, acc[tt].x);
          acc[tt].y = FDOT2(SH(w,1), zA01, acc[tt].y);
          acc[tt].x = FDOT2(SH(w,2), zA23, acc[tt].x);
          acc[tt].y = FDOT2(SH(w,3), zA23, acc[tt].y);
          acc[tt].z = FDOT2(SH(w,0), zB01, acc[tt].z);
          acc[tt].w = FDOT2(SH(w,1), zB01, acc[tt].w);
          acc[tt].z = FDOT2(SH(w,2), zB23, acc[tt].z);
          acc[tt].w = FDOT2(SH(w,3), zB23, acc[tt].w);
        }
      }
#pragma unroll
      for (int tt = 0; tt < 2; ++tt) {
        *(f32x2*)&xp[2*kh + tt][0][2*rg] = f32x2{acc[tt].x, acc[tt].y};
        *(f32x2*)&xp[2*kh + tt][1][2*rg] = f32x2{acc[tt].z, acc[tt].w};
      }
    }
    __syncthreads();

    const int tend = (t0 + CS < LL) ? t0 + CS : LL;
    for (int t = t0; t < tend; ++t) {
      const int uA = u_lds[0], uB = u_lds[1];

      if (uA | uB) {
        ustep++;
        const int buf = ustep & 1;

        // ---- P1: finalize pending gates: accS/part + bias + xp[t] -> act ----
        if (kh == 0) {
          f32x4 v = accS;
#pragma unroll
          for (int q = 0; q < 7; ++q) v += part[q][rg];
          const int tin = t - t0;
          const f32x2 xA = *(const f32x2*)&xp[tin][0][2*rg];
          const f32x2 xB = *(const f32x2*)&xp[tin][1][2*rg];
          float vA0 = v.x + bias2.x + xA.x;
          float vA1 = v.y + bias2.y + xA.y;
          float vB0 = v.z + bias2.x + xB.x;
          float vB1 = v.w + bias2.y + xB.y;
          const int gate = rg >> 5;            // rows 2rg,2rg+1: gate = (2rg)>>6
          if (gate == 2) {
            vA0 = tanhf(vA0); vA1 = tanhf(vA1); vB0 = tanhf(vB0); vB1 = tanhf(vB1);
          } else {
            vA0 = sigm(vA0); vA1 = sigm(vA1); vB0 = sigm(vB0); vB1 = sigm(vB1);
          }
          gown[0][2*rg] = vA0; gown[0][2*rg+1] = vA1;
          gown[1][2*rg] = vB0; gown[1][2*rg+1] = vB1;
        }
        __syncthreads();                        // (1) gown ready

        // ---- P2: updaters (tid<128) store stamped chunks || pollers read ----
        if (tid < 128) {
          const int b01 = tid >> 6, j = tid & 63;
          const float u = (float)(b01 ? uB : uA);   // exact for u in {0,1}
          const float ig = gown[b01][j],        fg = gown[b01][64 + j];
          const float gg = gown[b01][128 + j],  og = gown[b01][192 + j];
          const float cnew = fg*c_reg + ig*gg;
          const float ct = u*cnew + (1.f - u)*c_reg;
          const float ht = u*(og*tanhf(ct)) + (1.f - u)*h_out;
          c_reg = ct; h_out = ht;
          zsb[b01][64*s + j] = (_Float16)ht;
          // stamped h-chunk: {fp16 h(j), fp16 h(j+1), u32 ustep}; chunk id tid>>1
          const float h1 = __shfl_down(ht, 1);
          if ((tid & 1) == 0) {
            f16x2 hh2; hh2[0] = (_Float16)ht; hh2[1] = (_Float16)h1;
            f32x2 pkt;
            pkt.x = __builtin_bit_cast(float, hh2);
            pkt.y = __uint_as_float((unsigned)ustep);
            st8_sys(pay_own + (size_t)buf*PAYF + tid, pkt);
          }
          // du partial: 64-lane wave reduce per batch (wave 0 = A, wave 1 = B)
          float pp = ct * wuj;
#pragma unroll
          for (int off = 1; off < 64; off <<= 1) pp += __shfl_xor(pp, off);
          if ((tid & 63) == 0) {
            pw_l[b01] = pp;
            f32x2 pkt;
            pkt.x = pp;
            pkt.y = __uint_as_float((unsigned)ustep);
            st8_sys(pay_own + (size_t)buf*PAYF + 128 + (b01 << 1), pkt);
          }
        } else if (isPoll) {
          const float* a = pay_g + ((size_t)ps2*2 + buf)*PAYF + 2*pc;
          f32x2 r = ld8_sys(a);
          while (__float_as_uint(r.y) != (unsigned)ustep) {
            __builtin_amdgcn_s_sleep(1);
            r = ld8_sys(a);
          }
          if (pc < 64) {
            const int b01 = pc >> 5, j0 = (pc & 31)*2;
            *(f16x2*)&zsb[b01][64*ps2 + j0] = __builtin_bit_cast(f16x2, r.x);
          } else {
            dp[ps2][pc - 64] = r.x;
          }
        }
        __syncthreads();                        // (2) zs full, dp/pw_l ready

        // ---- P3: u decision (tid0, fixed slice order) || GEMV for next step ----
        if (tid == 0) {
#pragma unroll
          for (int bb = 0; bb < 2; ++bb) {
            float dot = 0.f;
#pragma unroll
            for (int q = 0; q < 8; ++q)
              dot += (q == s) ? pw_l[bb] : dp[q][bb];
            const float du = sigm(dot + buv);
            const float uo = (float)(bb ? uB : uA);
            const float utn = uo*du + (1.f - uo)*(utr[bb] + fminf(du, 1.f - utr[bb]));
            utr[bb] = utn; dotr[bb] = dot;
            u_lds[bb] = (int)rintf(utn);
          }
        }
        WHH_SLICE();                            // pending GEMV for step t+1
      } else {
        // ---- full skip: c,h,pending GEMV unchanged; ut/u advance (exact) ----
        if (tid == 0) {
#pragma unroll
          for (int bb = 0; bb < 2; ++bb) {
            const float du = sigm(dotr[bb] + buv);
            const float utn = utr[bb] + fminf(du, 1.f - utr[bb]);
            utr[bb] = utn;
            u_lds[bb] = (int)rintf(utn);
          }
        }
      }
      __syncthreads();                          // (3/end) u_lds, part[] visible
    }
  }

  // each block writes its disjoint 64-unit slice for its 2 batches
  if (tid < 128)
    out[(size_t)(bA + (tid >> 6))*HID + 64*s + (tid & 63)] = h_out;
}

extern "C" void kernel_launch(void* const* d_in, const int* in_sizes, int n_in,
                              void* d_out, int out_size, void* d_ws, size_t ws_size,
                              hipStream_t stream) {
  const float* x    = (const float*)d_in[0];
  const float* cw   = (const float*)d_in[1];
  const float* cb   = (const float*)d_in[2];
  const float* gma  = (const float*)d_in[3];
  const float* bta  = (const float*)d_in[4];
  const float* bmean= (const float*)d_in[5];
  const float* bvar = (const float*)d_in[6];
  const float* wih  = (const float*)d_in[7];
  const float* whh  = (const float*)d_in[8];
  const float* bih  = (const float*)d_in[9];
  const float* bhh  = (const float*)d_in[10];
  const float* wu   = (const float*)d_in[11];
  const float* bu   = (const float*)d_in[12];
  float* out = (float*)d_out;

  float* ws       = (float*)d_ws;
  float* seq      = ws;                                    // 8,355,840 f
  _Float16* whhP8 = (_Float16*)(seq + (size_t)BB*LL*NB);   // 2^20 halves (2 MB)
  _Float16* wihP8 = whhP8 + (size_t)8*NHH8;                // 2^19 halves (1 MB)
  float* biasvP8  = (float*)(wihP8 + (size_t)8*NIH8);      // 2048 f
  float* pay      = biasvP8 + ROWS;                        // 256*2*160 f (320 KB)

  // kill graph-replay stale stamps (deterministic, graph-safe)
  hipMemsetAsync(pay, 0, (size_t)256*2*PAYF*sizeof(float), stream);

  hipLaunchKernelGGL(prep_kernel,
                     dim3((8*NHH8 + 8*NIH8 + ROWS + 255)/256), dim3(256),
                     0, stream, wih, whh, bih, bhh, whhP8, wihP8, biasvP8);
  hipLaunchKernelGGL(conv_kernel, dim3(16, 64), dim3(256), 0, stream,
                     x, cw, cb, gma, bta, bmean, bvar, seq);
  hipLaunchKernelGGL(rec_kernel, dim3(256), dim3(1024), 0, stream,
                     seq, whhP8, wihP8, biasvP8, wu, bu, pay, out);
}